// Round 17
// baseline (246.097 us; speedup 1.0000x reference)
//
#include <hip/hip_runtime.h>
#include <math.h>

#define BATCH   16384
#define HD      24      // LSTM hidden size
#define NOUTC   24
#define NHID    16
#define NSTEPS  47
#define NG      96
#define GRP     16      // elements per block
#define NTG     24      // thread-groups per element: w owns j-slot w and logit col w
#define THREADS 384     // 6 waves; grid 1024 -> 4 blocks/CU, 24 waves/CU

typedef float v2f __attribute__((ext_vector_type(2)));
union F4 { float4 v; v2f h[2]; float f[4]; };

__device__ __forceinline__ v2f pk_fma(v2f a, v2f b, v2f c) {
    v2f d;
    asm("v_pk_fma_f32 %0, %1, %2, %3" : "=v"(d) : "v"(a), "v"(b), "v"(c));
    return d;  // per-component IEEE fma: bit-identical to 2x fmaf
}

__device__ __forceinline__ float fast_sigmoid(float x) {
    float t = __expf(-x);
    return __builtin_amdgcn_rcpf(1.0f + t);
}
__device__ __forceinline__ float fast_tanh(float x) {
    float ax = fabsf(x);
    float t  = __expf(-2.0f * ax);
    float r  = (1.0f - t) * __builtin_amdgcn_rcpf(1.0f + t);
    return copysignf(r, x);
}

// Odd-step finish over first T columns (T >= cnt; n in [cnt,T) contribute
// exact -INF/0 -> bit-identical to full 24-wide loop).
template <int T>
__device__ __forceinline__ void finish_odd(const float* sLrow, int cnt, float r,
                                           int& a, float& pr) {
    float v[T];
    #pragma unroll
    for (int n4 = 0; n4 < T / 4; ++n4) {
        F4 vv; vv.v = *(const float4*)&sLrow[n4 * 4];
        v[n4 * 4 + 0] = vv.f[0]; v[n4 * 4 + 1] = vv.f[1];
        v[n4 * 4 + 2] = vv.f[2]; v[n4 * 4 + 3] = vv.f[3];
    }
    float m = -INFINITY;
    #pragma unroll
    for (int n = 0; n < T; ++n) m = fmaxf(m, (n < cnt) ? v[n] : -INFINITY);
    #pragma unroll
    for (int n = 0; n < T; ++n) v[n] = (n < cnt) ? __expf(v[n] - m) : 0.f;
    float Z = 0.f;
    #pragma unroll
    for (int n = 0; n < T; ++n) Z += v[n];         // sequential ascending
    const float rZ = r * Z;
    float cum = 0.f, ea = 0.f;
    bool found = false;
    a = 0;
    #pragma unroll
    for (int n = 0; n < T; ++n) {
        cum += v[n];
        if (!found && cum > rZ) { found = true; a = n; ea = v[n]; }
    }
    if (!found) { a = 0; ea = v[0]; }              // n=0 always unmasked (cnt>=1)
    pr = ea / Z;                                   // IEEE div, mirrors reference
}

__global__ __launch_bounds__(THREADS, 6) void policy_kernel(
    const float* __restrict__ W_ih, const float* __restrict__ W_hh,
    const float* __restrict__ b_ih, const float* __restrict__ b_hh,
    const float* __restrict__ Wl,   const float* __restrict__ bl,
    const float* __restrict__ rnd,  float* __restrict__ out)
{
    __shared__ float sWihB[NG][25];                    // [g][c] + bias folded (gather)
    __shared__ float sBias[NG];                        // b_ih + b_hh (step 0)
    __shared__ __align__(16) float sWhhG[HD][NTG][4];  // [k][w][t] = W_hh[t*24+w][k]
    __shared__ __align__(16) float sWlT[NTG][28];      // [w][k] = Wl[w][k] (row 112B, 16B-aligned)
    __shared__ float sBl[NOUTC];
    __shared__ __align__(16) float hhT[GRP][28];       // [e][k] h (single buffer)
    __shared__ __align__(16) float sLt[GRP][28];       // [e][n] logits
    __shared__ float sPr[GRP][NSTEPS + 1];
    __shared__ unsigned char sAct8[GRP][NSTEPS + 1];

    const int tid = threadIdx.x;
    const int w   = tid >> 4;               // 0..23: j-slot + logit column owner
    const int e   = tid & 15;               // element within group
    const int wv  = tid >> 6;               // wave 0..5 (owns logit cols [4wv,4wv+4))
    const int b   = blockIdx.x * GRP + e;

    // ---- staging (once per block) ----
    for (int i = tid; i < NG * HD; i += THREADS) {
        int g = i / HD, k = i % HD;
        float bs = b_ih[g] + b_hh[g];
        sWihB[g][k] = W_ih[i] + bs;
        sWhhG[k][g % 24][g / 24] = W_hh[i];
    }
    for (int i = tid; i < NOUTC * HD; i += THREADS) {
        int n = i / HD, k = i % HD;
        sWlT[n][k] = Wl[i];
    }
    if (tid < NG)    sBias[tid] = b_ih[tid] + b_hh[tid];
    if (tid < NOUTC) sBl[tid]   = bl[tid];
    __syncthreads();

    float cstw = 0.f;                        // own j-slot cell state
    v2f accA = (v2f){0.f, 0.f};              // gates (i=w, f=24+w); h0=0 -> exact 0
    v2f accB = (v2f){0.f, 0.f};              // gates (g=48+w, o=72+w)
    int actE = 0;

    for (int s = 0; s < NSTEPS; ++s) {
        const float r   = rnd[s * BATCH + b];
        const int   cnt = (s + 1) >> 1;
        const bool  odd = (s & 1) != 0;

        // ---- complete gates: GEMV-partial + gather row (bias folded) ----
        float g0, g1, g2, g3;
        if (s == 0) {
            g0 = accA.x + sBias[w];      g1 = accA.y + sBias[24 + w];
            g2 = accB.x + sBias[48 + w]; g3 = accB.y + sBias[72 + w];
        } else {
            g0 = accA.x + sWihB[w][actE];      g1 = accA.y + sWihB[24 + w][actE];
            g2 = accB.x + sWihB[48 + w][actE]; g3 = accB.y + sWihB[72 + w][actE];
        }

        // ---- LSTM cell for own j-slot ----
        {
            float si = fast_sigmoid(g0);
            float sf = fast_sigmoid(g1);
            float tg = fast_tanh(g2);
            float so = fast_sigmoid(g3);
            float cj = sf * cstw + si * tg;
            cstw = cj;
            hhT[e][w] = so * fast_tanh(cj);
        }
        __syncthreads();   // B: new h visible

        // ---- merged k-loop: logit col w (s) + 4-gate GEMV (s+1) ----
        const bool doLog = odd ? (4 * wv < cnt) : (wv >= 4);
        accA = (v2f){0.f, 0.f};
        accB = (v2f){0.f, 0.f};
        float l = 0.f;
        #pragma unroll 2
        for (int c = 0; c < 6; ++c) {
            F4 hx; hx.v = *(const float4*)&hhT[e][c * 4];
            F4 wl;
            if (doLog) wl.v = *(const float4*)&sWlT[w][c * 4];
            #pragma unroll
            for (int q = 0; q < 4; ++q) {
                int k = c * 4 + q;
                float hk = hx.f[q];
                v2f hk2; hk2.x = hk; hk2.y = hk;
                F4 u; u.v = *(const float4*)&sWhhG[k][w][0];
                accA = pk_fma(hk2, u.h[0], accA);
                accB = pk_fma(hk2, u.h[1], accB);
                if (doLog) l = fmaf(hk, wl.f[q], l);   // k-ascending scalar chain
            }
        }
        if (doLog) sLt[e][w] = l + sBl[w];
        __syncthreads();   // C: logits visible

        // ---- redundant finish (tiered on odd steps; bit-exact) ----
        int a;
        float pr;
        if (odd) {
            if (cnt <= 8)       finish_odd<8 >(&sLt[e][0], cnt, r, a, pr);
            else if (cnt <= 16) finish_odd<16>(&sLt[e][0], cnt, r, a, pr);
            else                finish_odd<24>(&sLt[e][0], cnt, r, a, pr);
        } else {
            float v8[8];
            {
                F4 x0, x1;
                x0.v = *(const float4*)&sLt[e][16];
                x1.v = *(const float4*)&sLt[e][20];
                #pragma unroll
                for (int i = 0; i < 4; ++i) { v8[i] = x0.f[i]; v8[4 + i] = x1.f[i]; }
            }
            float m = -INFINITY;
            #pragma unroll
            for (int i = 0; i < 8; ++i) m = fmaxf(m, v8[i]);
            #pragma unroll
            for (int i = 0; i < 8; ++i) v8[i] = __expf(v8[i] - m);
            float Z = 0.f;
            #pragma unroll
            for (int i = 0; i < 8; ++i) Z += v8[i];            // sequential 16..23
            const float rZ = r * Z;
            float cum = 0.f, ea = 0.f;
            bool found = false;
            a = 0;
            #pragma unroll
            for (int i = 0; i < 8; ++i) {
                cum += v8[i];
                if (!found && cum > rZ) { found = true; a = NHID + i; ea = v8[i]; }
            }
            if (!found) { a = 0; ea = 0.f; }                   // ref: p[0]=0 on even steps
            pr = ea / Z;
        }

        if (w == 0) { sPr[e][s] = pr; sAct8[e][s] = (unsigned char)a; }
        actE = a;                                              // identical across all 24 groups
    }

    __syncthreads();
    // ---- coalesced write-out ----
    const int base = blockIdx.x * GRP * NSTEPS;
    for (int i = tid; i < GRP * NSTEPS; i += THREADS) {
        int rr = i / NSTEPS, ss = i - rr * NSTEPS;
        out[base + i]                          = sPr[rr][ss];
        out[(size_t)BATCH * NSTEPS + base + i] = (float)sAct8[rr][ss];
    }
}

extern "C" void kernel_launch(void* const* d_in, const int* in_sizes, int n_in,
                              void* d_out, int out_size, void* d_ws, size_t ws_size,
                              hipStream_t stream) {
    const float* W_ih = (const float*)d_in[0];
    const float* W_hh = (const float*)d_in[1];
    const float* b_ih = (const float*)d_in[2];
    const float* b_hh = (const float*)d_in[3];
    const float* Wl   = (const float*)d_in[4];
    const float* bl   = (const float*)d_in[5];
    const float* rnd  = (const float*)d_in[6];
    float* o = (float*)d_out;

    policy_kernel<<<BATCH / GRP, THREADS, 0, stream>>>(W_ih, W_hh, b_ih, b_hh, Wl, bl, rnd, o);
}

// Round 18
// 145.073 us; speedup vs baseline: 1.6964x; 1.6964x over previous
//
#include <hip/hip_runtime.h>
#include <math.h>

#define BATCH   16384
#define HD      24      // LSTM hidden size
#define NOUTC   24
#define NHID    16
#define NSTEPS  47
#define NG      96
#define GRP     16      // elements per block
#define NTG     12      // thread-groups per element
#define JPW     2       // j-slots per thread-group
#define GPW     8       // gates per thread-group
#define THREADS 192     // 3 waves; grid 1024 -> 4 blocks/CU, 12 waves/CU

typedef float v2f __attribute__((ext_vector_type(2)));
union F4 { float4 v; v2f h[2]; float f[4]; };

__device__ __forceinline__ v2f pk_fma(v2f a, v2f b, v2f c) {
    v2f d;
    asm("v_pk_fma_f32 %0, %1, %2, %3" : "=v"(d) : "v"(a), "v"(b), "v"(c));
    return d;  // per-component IEEE fma: bit-identical to 2x fmaf
}

__device__ __forceinline__ float fast_sigmoid(float x) {
    float t = __expf(-x);
    return __builtin_amdgcn_rcpf(1.0f + t);
}
__device__ __forceinline__ float fast_tanh(float x) {
    float ax = fabsf(x);
    float t  = __expf(-2.0f * ax);
    float r  = (1.0f - t) * __builtin_amdgcn_rcpf(1.0f + t);
    return copysignf(r, x);
}

// Odd-step finish over first T columns (T >= cnt; n in [cnt,T) contribute
// exact -INF/0 -> bit-identical to the full 24-wide loop).
template <int T>
__device__ __forceinline__ void finish_odd(const float* sLrow, int cnt, float r,
                                           int& a, float& pr) {
    float v[T];
    #pragma unroll
    for (int n4 = 0; n4 < T / 4; ++n4) {
        F4 vv; vv.v = *(const float4*)&sLrow[n4 * 4];
        v[n4 * 4 + 0] = vv.f[0]; v[n4 * 4 + 1] = vv.f[1];
        v[n4 * 4 + 2] = vv.f[2]; v[n4 * 4 + 3] = vv.f[3];
    }
    float m = -INFINITY;
    #pragma unroll
    for (int n = 0; n < T; ++n) m = fmaxf(m, (n < cnt) ? v[n] : -INFINITY);
    #pragma unroll
    for (int n = 0; n < T; ++n) v[n] = (n < cnt) ? __expf(v[n] - m) : 0.f;
    float Z = 0.f;
    #pragma unroll
    for (int n = 0; n < T; ++n) Z += v[n];         // sequential ascending
    const float rZ = r * Z;
    float cum = 0.f, ea = 0.f;
    bool found = false;
    a = 0;
    #pragma unroll
    for (int n = 0; n < T; ++n) {
        cum += v[n];
        if (!found && cum > rZ) { found = true; a = n; ea = v[n]; }
    }
    if (!found) { a = 0; ea = v[0]; }              // n=0 always unmasked (cnt>=1)
    pr = ea / Z;                                   // IEEE div, mirrors reference
}

__global__ __launch_bounds__(THREADS, 3) void policy_kernel(
    const float* __restrict__ W_ih, const float* __restrict__ W_hh,
    const float* __restrict__ b_ih, const float* __restrict__ b_hh,
    const float* __restrict__ Wl,   const float* __restrict__ bl,
    const float* __restrict__ rnd,  float* __restrict__ out)
{
    __shared__ float sWihB[NG][25];          // [g][c] + bias folded (gather)
    __shared__ float sBias[NG];              // b_ih + b_hh (step 0)
    __shared__ __align__(16) float sWhhP[HD][NTG][GPW];  // [k][w][t*2+i] : gate g = t*24+w*2+i
    __shared__ __align__(8)  float sWlP[HD][NTG][JPW];   // [k][w][i] : logit col n = w*2+i
    __shared__ float sBl[NOUTC];
    __shared__ __align__(16) float hhT[GRP][28];         // [e][k] h (single buffer)
    __shared__ __align__(16) float sLt[GRP][28];         // [e][n] logits
    __shared__ float sPr[GRP][NSTEPS + 1];
    __shared__ unsigned char sAct8[GRP][NSTEPS + 1];
    __shared__ int sActCur[GRP];

    const int tid = threadIdx.x;
    const int w   = tid >> 4;                // thread-group 0..11
    const int e   = tid & 15;                // element within group
    const int wv  = tid >> 6;                // wave 0..2 (owns logit cols [8wv,8wv+8))
    const int b   = blockIdx.x * GRP + e;

    // ---- staging (once per block) ----
    for (int i = tid; i < NG * HD; i += THREADS) {
        int g = i / HD, k = i % HD;
        float bs = b_ih[g] + b_hh[g];
        sWihB[g][k] = W_ih[i] + bs;
        int t = g / 24, rem = g % 24;
        sWhhP[k][rem >> 1][t * JPW + (rem & 1)] = W_hh[i];
    }
    for (int i = tid; i < NOUTC * HD; i += THREADS) {
        int n = i / HD, k = i % HD;
        sWlP[k][n >> 1][n & 1] = Wl[i];
    }
    if (tid < NG)    sBias[tid] = b_ih[tid] + b_hh[tid];
    if (tid < NOUTC) sBl[tid]   = bl[tid];
    __syncthreads();

    // ---- prologue: cell(0) with gates = bias (h-term = 0 exactly) ----
    float cst[JPW] = {0.f, 0.f};
    {
        float h0, h1;
        #pragma unroll
        for (int i = 0; i < JPW; ++i) {
            float g0 = sBias[0 * 24 + w * JPW + i];
            float g1 = sBias[1 * 24 + w * JPW + i];
            float g2 = sBias[2 * 24 + w * JPW + i];
            float g3 = sBias[3 * 24 + w * JPW + i];
            float si = fast_sigmoid(g0);
            float sf = fast_sigmoid(g1);
            float tg = fast_tanh(g2);
            float so = fast_sigmoid(g3);
            float cj = sf * cst[i] + si * tg;
            cst[i] = cj;
            float hv = so * fast_tanh(cj);
            if (i == 0) h0 = hv; else h1 = hv;
        }
        *(float2*)&hhT[e][2 * w] = make_float2(h0, h1);
    }
    __syncthreads();   // B: h(0) visible

    v2f aN[4];

    for (int s = 0; s < NSTEPS; ++s) {
        const int  cnt = (s + 1) >> 1;
        const bool odd = (s & 1) != 0;
        float r = 0.f;
        if (w == 0) r = rnd[s * BATCH + b];        // only finish consumes rnd

        // ---- L: logits(s) from h(s) (masked columns skipped, wave-uniform) ----
        const bool doLog = odd ? (8 * wv < cnt) : (wv == 2);
        if (doLog) {
            v2f aL = (v2f){0.f, 0.f};
            #pragma unroll
            for (int c = 0; c < 6; ++c) {
                F4 hx; hx.v = *(const float4*)&hhT[e][c * 4];
                #pragma unroll
                for (int q = 0; q < 4; ++q) {
                    int k = c * 4 + q;
                    v2f hk2; hk2.x = hx.f[q]; hk2.y = hx.f[q];
                    v2f lv = *(const v2f*)&sWlP[k][w][0];
                    aL = pk_fma(hk2, lv, aL);      // k-ascending, same chain as R15
                }
            }
            sLt[e][w * JPW + 0] = aL.x + sBl[w * JPW + 0];
            sLt[e][w * JPW + 1] = aL.y + sBl[w * JPW + 1];
        }
        __syncthreads();   // C1: logits visible

        // ---- F: deduped finish (w==0 lanes) — hidden under G ----
        if (w == 0) {
            int a;
            float pr;
            if (odd) {
                if (cnt <= 8)       finish_odd<8 >(&sLt[e][0], cnt, r, a, pr);
                else if (cnt <= 16) finish_odd<16>(&sLt[e][0], cnt, r, a, pr);
                else                finish_odd<24>(&sLt[e][0], cnt, r, a, pr);
            } else {
                float v8[8];
                {
                    F4 x0, x1;
                    x0.v = *(const float4*)&sLt[e][16];
                    x1.v = *(const float4*)&sLt[e][20];
                    #pragma unroll
                    for (int i = 0; i < 4; ++i) { v8[i] = x0.f[i]; v8[4 + i] = x1.f[i]; }
                }
                float m = -INFINITY;
                #pragma unroll
                for (int i = 0; i < 8; ++i) m = fmaxf(m, v8[i]);
                #pragma unroll
                for (int i = 0; i < 8; ++i) v8[i] = __expf(v8[i] - m);
                float Z = 0.f;
                #pragma unroll
                for (int i = 0; i < 8; ++i) Z += v8[i];        // sequential 16..23
                const float rZ = r * Z;
                float cum = 0.f, ea = 0.f;
                bool found = false;
                a = 0;
                #pragma unroll
                for (int i = 0; i < 8; ++i) {
                    cum += v8[i];
                    if (!found && cum > rZ) { found = true; a = NHID + i; ea = v8[i]; }
                }
                if (!found) { a = 0; ea = 0.f; }               // ref: p[0]=0 on even steps
                pr = ea / Z;
            }
            sPr[e][s]   = pr;
            sAct8[e][s] = (unsigned char)a;
            sActCur[e]  = a;
        }

        // ---- G: gates h-term GEMV(s+1) from h(s) — needs no act ----
        #pragma unroll
        for (int q = 0; q < 4; ++q) aN[q] = (v2f){0.f, 0.f};
        #pragma unroll 2
        for (int c = 0; c < 6; ++c) {
            F4 hx; hx.v = *(const float4*)&hhT[e][c * 4];
            #pragma unroll
            for (int q = 0; q < 4; ++q) {
                int k = c * 4 + q;
                v2f hk2; hk2.x = hx.f[q]; hk2.y = hx.f[q];
                const float* wp = &sWhhP[k][w][0];
                F4 u0, u1;
                u0.v = *(const float4*)&wp[0];
                u1.v = *(const float4*)&wp[4];
                aN[0] = pk_fma(hk2, u0.h[0], aN[0]);
                aN[1] = pk_fma(hk2, u0.h[1], aN[1]);
                aN[2] = pk_fma(hk2, u1.h[0], aN[2]);
                aN[3] = pk_fma(hk2, u1.h[1], aN[3]);
            }
        }
        __syncthreads();   // C2: act visible; h(s) reads complete

        // ---- A: act -> gather + cell(s+1) -> h(s+1) ----
        {
            const int actE = sActCur[e];           // broadcast read (same addr for 12 groups)
            float h0, h1;
            #pragma unroll
            for (int i = 0; i < JPW; ++i) {
                float g0 = ((i == 0) ? aN[0].x : aN[0].y) + sWihB[0 * 24 + w * JPW + i][actE];
                float g1 = ((i == 0) ? aN[1].x : aN[1].y) + sWihB[1 * 24 + w * JPW + i][actE];
                float g2 = ((i == 0) ? aN[2].x : aN[2].y) + sWihB[2 * 24 + w * JPW + i][actE];
                float g3 = ((i == 0) ? aN[3].x : aN[3].y) + sWihB[3 * 24 + w * JPW + i][actE];
                float si = fast_sigmoid(g0);
                float sf = fast_sigmoid(g1);
                float tg = fast_tanh(g2);
                float so = fast_sigmoid(g3);
                float cj = sf * cst[i] + si * tg;
                cst[i] = cj;
                float hv = so * fast_tanh(cj);
                if (i == 0) h0 = hv; else h1 = hv;
            }
            *(float2*)&hhT[e][2 * w] = make_float2(h0, h1);   // h(s+1); s=46 write unused
        }
        __syncthreads();   // B: h(s+1) visible
    }

    // ---- coalesced write-out ----
    const int base = blockIdx.x * GRP * NSTEPS;
    for (int i = tid; i < GRP * NSTEPS; i += THREADS) {
        int rr = i / NSTEPS, ss = i - rr * NSTEPS;
        out[base + i]                          = sPr[rr][ss];
        out[(size_t)BATCH * NSTEPS + base + i] = (float)sAct8[rr][ss];
    }
}

extern "C" void kernel_launch(void* const* d_in, const int* in_sizes, int n_in,
                              void* d_out, int out_size, void* d_ws, size_t ws_size,
                              hipStream_t stream) {
    const float* W_ih = (const float*)d_in[0];
    const float* W_hh = (const float*)d_in[1];
    const float* b_ih = (const float*)d_in[2];
    const float* b_hh = (const float*)d_in[3];
    const float* Wl   = (const float*)d_in[4];
    const float* bl   = (const float*)d_in[5];
    const float* rnd  = (const float*)d_in[6];
    float* o = (float*)d_out;

    policy_kernel<<<BATCH / GRP, THREADS, 0, stream>>>(W_ih, W_hh, b_ih, b_hh, Wl, bl, rnd, o);
}